// Round 18
// baseline (390.772 us; speedup 1.0000x reference)
//
#include <hip/hip_runtime.h>
#include <math.h>
#include <stdint.h>

// Fused pipeline (E=300000, ND=100000, FEAT=256, RDIM=128):
//   prep:   weights -> bf16 fragment-ordered tables (plain k order)
//   CSR:    hist, scan, scan_bsum, add_offsets, build_sorted (dst-sorted rid_s/esrc_s)
//   fused (512 thr = 8 waves, one per 32-col slice f; 64 edges/block as TWO
//          groups; weight frag loaded once per ks, reused across groups (R16).
//          8 thin waves instead of 4 fat ones: acc = 2 x f32x16 = 32 AGPR ->
//          fits launch_bounds(512,4) budget 128 with NO spill (R13/R16 lesson:
//          the 4-wave form needs 140 regs and caps at 3 blk/CU = 12 waves;
//          this form gives 16 waves/CU). LDS 48.5KB.
//     stage: block's 64 remb rows loaded COALESCED -> cvt_pk -> t_rb bf16
//     s1 (swapped mfma, K=128): pa/ra dots ONLY f==0 wave; ga->global, gvb->LDS
//     s2 (swapped, K=256):      t2 = gelu(W2 @ t1)  (t_lds in-place)
//     s3 (normal, K=256):       m = (t2 @ W3^T)*gvb; epilogue pairs (col,col+1)
//         via shfl_xor(1); even lanes store b32 pairs in TRUE column order
//   segsum: h[d] = sum_i ( m[i] + ga[i]*feat[src_i] ) — one float4 feat load +
//           one ushort4 m load per edge-lane; 4-wide masked unroll
//   g4:     out = (h @ lin_w^T)*ci + b
// GELU = x*sigmoid(1.702x) (5 ops; err O(x^3) at |x|<~0.1 -> negligible).
// Swizzles: 16B-slot XOR with row&15 (<=2-way conflicts, free per m136).
// mfma_f32_32x32x16_bf16 layouts (HW-validated R2-R17):
//   A: row=lane&31, k=8*(lane>>5)+j ; B: col=lane&31, same k
//   D: col=lane&31, row=(reg&3)+8*(reg>>2)+4*(lane>>5)

typedef short bf16x8 __attribute__((ext_vector_type(8)));
typedef float f32x16 __attribute__((ext_vector_type(16)));

__device__ __forceinline__ float bf2f(unsigned short v) {
    union { unsigned int u; float f; } x; x.u = ((unsigned int)v) << 16; return x.f;
}
__device__ __forceinline__ unsigned short f2bf(float f) {
    union { float f; unsigned int u; } x; x.f = f;
    unsigned int u = x.u;
    return (unsigned short)((u + 0x7FFFu + ((u >> 16) & 1u)) >> 16);
}
// single-instruction packed f32x2 -> bf16x2 (RTNE), low16 = lo
__device__ __forceinline__ unsigned pack2(float lo, float hi) {
    unsigned r;
    asm("v_cvt_pk_bf16_f32 %0, %1, %2" : "=v"(r) : "v"(lo), "v"(hi));
    return r;
}
// sigmoid-form GELU: x * sigmoid(1.702 x)
__device__ __forceinline__ float gelu_fast(float x) {
    float e = __builtin_amdgcn_exp2f(x * -2.4554912f);   // exp(-1.702x)
    return x * __builtin_amdgcn_rcpf(e + 1.0f);
}
__device__ __forceinline__ float sigmoidf(float x) {
    return 1.0f / (1.0f + expf(-x));
}

// weights -> bf16 fragment-ordered tables (ALL plain k order)
__global__ __launch_bounds__(256) void prep_weights(
    const float* __restrict__ rw1, const float* __restrict__ rw2,
    const float* __restrict__ rw3, const float* __restrict__ lw,
    unsigned short* __restrict__ w1s, unsigned short* __restrict__ w2s,
    unsigned short* __restrict__ w3s, unsigned short* __restrict__ lws)
{
    int i = blockIdx.x * blockDim.x + threadIdx.x;
    int j   = i & 7;
    int l   = (i >> 3) & 31;
    int kgg = (i >> 8) & 1;
    int n2  = (i >> 9) & 7;
    int ks  = i >> 12;
    if (i < 32768) {   // K=128: ks 0..7
        w1s[i] = f2bf(rw1[(n2 * 32 + l) * 128 + ks * 16 + kgg * 8 + j]);
    }
    if (i < 65536) {   // K=256: ks 0..15
        int row = n2 * 32 + l, k = ks * 16 + kgg * 8 + j;
        w2s[i] = f2bf(rw2[(size_t)row * 256 + k]);
        w3s[i] = f2bf(rw3[(size_t)row * 256 + k]);
        lws[i] = f2bf(lw[(size_t)row * 256 + k]);
    }
}

// fragment load from pre-swizzled table (contiguous, coalesced)
__device__ __forceinline__ bf16x8 ldw(const unsigned short* __restrict__ W,
                                      int ks, int nglob, int kg, int l31) {
    return *(const bf16x8*)(W + (((((ks * 8 + nglob) * 2) + kg) * 32 + l31) << 3));
}

// ---------------- CSR build ----------------
__global__ __launch_bounds__(256) void hist_kernel(
    const int* __restrict__ edst, int* __restrict__ cnt,
    int* __restrict__ within, int E)
{
    int e = blockIdx.x * blockDim.x + threadIdx.x;
    if (e < E) within[e] = atomicAdd(&cnt[edst[e]], 1);
}

__global__ __launch_bounds__(1024) void scan_block(
    const int* __restrict__ cnt, int* __restrict__ start,
    int* __restrict__ bsum, int n)
{
    __shared__ int s[1024];
    int gid = blockIdx.x * 1024 + threadIdx.x;
    int v = (gid < n) ? cnt[gid] : 0;
    s[threadIdx.x] = v;
    __syncthreads();
    #pragma unroll
    for (int off = 1; off < 1024; off <<= 1) {
        int t = (threadIdx.x >= off) ? s[threadIdx.x - off] : 0;
        __syncthreads();
        if (threadIdx.x >= off) s[threadIdx.x] += t;
        __syncthreads();
    }
    if (gid < n) start[gid] = s[threadIdx.x] - v;   // exclusive
    if (threadIdx.x == 1023) bsum[blockIdx.x] = s[1023];
}

__global__ void scan_bsum(int* __restrict__ bsum, int nb) {
    if (threadIdx.x == 0 && blockIdx.x == 0) {
        int acc = 0;
        for (int i = 0; i < nb; ++i) { int v = bsum[i]; bsum[i] = acc; acc += v; }
    }
}

__global__ __launch_bounds__(1024) void add_offsets(
    int* __restrict__ start, const int* __restrict__ bsum, int n, int E)
{
    int gid = blockIdx.x * 1024 + threadIdx.x;
    if (gid < n) start[gid] += bsum[gid >> 10];
    if (gid == 0) start[n] = E;
}

// counting sort: directly emit dst-sorted rid/esrc
__global__ __launch_bounds__(256) void build_sorted(
    const int* __restrict__ edst, const int* __restrict__ within,
    const int* __restrict__ start, const int* __restrict__ rid,
    const int* __restrict__ esrc, int* __restrict__ rid_s,
    int* __restrict__ esrc_s, int E)
{
    int e = blockIdx.x * blockDim.x + threadIdx.x;
    if (e < E) {
        int pos = start[edst[e]] + within[e];
        rid_s[pos]  = rid[e];
        esrc_s[pos] = esrc[e];
    }
}

// ---------------- LDS helpers (16B-slot XOR swizzle, row&15) ----------------
__device__ __forceinline__ bf16x8 ldtf(const unsigned short* t_lds, int row, int ks, int kg) {
    int slot = (ks * 2 + kg) ^ (row & 15);
    return *(const bf16x8*)((const char*)t_lds + row * 512 + slot * 16);
}
__device__ __forceinline__ void sttf(unsigned short* t_lds, int row, int nn, int p, int kg, uint2 w) {
    int slot = (nn * 4 + p) ^ (row & 15);
    *(uint2*)((char*)t_lds + row * 512 + slot * 16 + kg * 8) = w;
}
__device__ __forceinline__ bf16x8 ldrb(const unsigned short* t_rb, int row, int ks, int kg) {
    int slot = (ks * 2 + kg) ^ (row & 15);
    return *(const bf16x8*)((const char*)t_rb + row * 256 + slot * 16);
}

// ------- fused g1+g2+g3 (8 thin waves, 2 edge-groups, weight-frag reuse) -------
__global__ __launch_bounds__(512, 4) void fused_edge(
    const float* __restrict__ remb, const int* __restrict__ rid_s,
    const int* __restrict__ esrc_s,
    const unsigned short* __restrict__ w1s, const unsigned short* __restrict__ w2s,
    const unsigned short* __restrict__ w3s,
    const float* __restrict__ pw, const float* __restrict__ sw,
    const float* __restrict__ cj, float* __restrict__ ga,
    unsigned short* __restrict__ m, int E)
{
    __shared__ __align__(16) unsigned short t_lds[64 * 256];   // 32 KB
    __shared__ __align__(16) unsigned short t_rb[64 * 128];    // 16 KB bf16 remb
    __shared__ float gvb_lds[64];

    const int lane = threadIdx.x & 63;
    const int f    = threadIdx.x >> 6;       // wave = 32-col slice 0..7
    const int l31  = lane & 31;
    const int kg   = lane >> 5;              // 0..1
    const int blk0 = blockIdx.x * 64;

    // ---- stage 64 remb rows coalesced -> t_rb (bf16) ----
    {
        const int t = threadIdx.x;
        #pragma unroll
        for (int p = 0; p < 2; ++p) {
            int sIdx = p * 512 + t;              // 0..1023
            int row  = sIdx >> 4;                // 0..63
            int c16  = sIdx & 15;                // 16B slot within row
            int gr   = blk0 + row;
            int rr   = rid_s[(gr < E) ? gr : (E - 1)];
            const float* sp = remb + (size_t)rr * 128 + c16 * 8;
            float4 a = *(const float4*)sp;
            float4 b = *(const float4*)(sp + 4);
            uint4 w;
            w.x = pack2(a.x, a.y); w.y = pack2(a.z, a.w);
            w.z = pack2(b.x, b.y); w.w = pack2(b.z, b.w);
            int slot = c16 ^ (row & 15);
            *(uint4*)((char*)t_rb + row * 256 + slot * 16) = w;
        }
    }
    __syncthreads();

    // ================= stage 1: swapped, K=128 (+ dots in f==0) =================
    {
        f32x16 acc[2];
        acc[0] = (f32x16)0.0f; acc[1] = (f32x16)0.0f;
        float pd0 = 0.f, rd0 = 0.f, pd1 = 0.f, rd1 = 0.f;

        #pragma unroll
        for (int ks = 0; ks < 8; ++ks) {
            bf16x8 wf = ldw(w1s, ks, f, kg, l31);
            #pragma unroll
            for (int g = 0; g < 2; ++g) {
                bf16x8 af = ldrb(t_rb, g * 32 + l31, ks, kg);
                if (f == 0) {   // wave-uniform: only f==0 pays for the dots
                    const int kk = ks * 16 + kg * 8;
                    float4 p0 = *(const float4*)(pw + kk), p1 = *(const float4*)(pw + kk + 4);
                    float4 s0 = *(const float4*)(sw + kk), s1v = *(const float4*)(sw + kk + 4);
                    float v0 = bf2f((unsigned short)af[0]), v1 = bf2f((unsigned short)af[1]);
                    float v2 = bf2f((unsigned short)af[2]), v3 = bf2f((unsigned short)af[3]);
                    float v4 = bf2f((unsigned short)af[4]), v5 = bf2f((unsigned short)af[5]);
                    float v6 = bf2f((unsigned short)af[6]), v7 = bf2f((unsigned short)af[7]);
                    float dp = v0*p0.x + v1*p0.y + v2*p0.z + v3*p0.w
                             + v4*p1.x + v5*p1.y + v6*p1.z + v7*p1.w;
                    float dr = v0*s0.x + v1*s0.y + v2*s0.z + v3*s0.w
                             + v4*s1v.x + v5*s1v.y + v6*s1v.z + v7*s1v.w;
                    if (g == 0) { pd0 += dp; rd0 += dr; } else { pd1 += dp; rd1 += dr; }
                }
                acc[g] = __builtin_amdgcn_mfma_f32_32x32x16_bf16(wf, af, acc[g], 0, 0, 0);
            }
        }

        if (f == 0) {
            pd0 += __shfl_xor(pd0, 32); rd0 += __shfl_xor(rd0, 32);
            pd1 += __shfl_xor(pd1, 32); rd1 += __shfl_xor(rd1, 32);
            if (lane < 32) {
                int i0 = blk0 + l31, i1 = blk0 + 32 + l31;
                float cj0 = cj[esrc_s[(i0 < E) ? i0 : (E - 1)]];
                float cj1 = cj[esrc_s[(i1 < E) ? i1 : (E - 1)]];
                if (i0 < E) ga[i0] = sigmoidf(pd0) * cj0;
                if (i1 < E) ga[i1] = sigmoidf(pd1) * cj1;
                gvb_lds[l31]      = sigmoidf(rd0) * cj0;
                gvb_lds[32 + l31] = sigmoidf(rd1) * cj1;
            }
        }

        #pragma unroll
        for (int g = 0; g < 2; ++g)
            #pragma unroll
            for (int p = 0; p < 4; ++p) {
                uint2 w;
                w.x = pack2(gelu_fast(acc[g][4*p + 0]), gelu_fast(acc[g][4*p + 1]));
                w.y = pack2(gelu_fast(acc[g][4*p + 2]), gelu_fast(acc[g][4*p + 3]));
                sttf(t_lds, g * 32 + l31, f, p, kg, w);
            }
    }
    __syncthreads();

    // ================= stage 2: swapped, K=256, LDS in-place =================
    {
        f32x16 acc[2];
        acc[0] = (f32x16)0.0f; acc[1] = (f32x16)0.0f;

        #pragma unroll
        for (int ks = 0; ks < 16; ++ks) {
            bf16x8 wf = ldw(w2s, ks, f, kg, l31);
            #pragma unroll
            for (int g = 0; g < 2; ++g) {
                bf16x8 tf = ldtf(t_lds, g * 32 + l31, ks, kg);
                acc[g] = __builtin_amdgcn_mfma_f32_32x32x16_bf16(wf, tf, acc[g], 0, 0, 0);
            }
        }
        __syncthreads();   // all reads of t1 done before overwrite
        #pragma unroll
        for (int g = 0; g < 2; ++g)
            #pragma unroll
            for (int p = 0; p < 4; ++p) {
                uint2 w;
                w.x = pack2(gelu_fast(acc[g][4*p + 0]), gelu_fast(acc[g][4*p + 1]));
                w.y = pack2(gelu_fast(acc[g][4*p + 2]), gelu_fast(acc[g][4*p + 3]));
                sttf(t_lds, g * 32 + l31, f, p, kg, w);
            }
    }
    __syncthreads();

    // ============ stage 3: normal, K=256, m = rf*gvb (true col order) ============
    {
        f32x16 acc[2];
        acc[0] = (f32x16)0.0f; acc[1] = (f32x16)0.0f;

        #pragma unroll
        for (int ks = 0; ks < 16; ++ks) {
            bf16x8 wf = ldw(w3s, ks, f, kg, l31);
            #pragma unroll
            for (int g = 0; g < 2; ++g) {
                bf16x8 tf = ldtf(t_lds, g * 32 + l31, ks, kg);
                acc[g] = __builtin_amdgcn_mfma_f32_32x32x16_bf16(tf, wf, acc[g], 0, 0, 0);
            }
        }

        // epilogue: pair (col, col+1) via shfl_xor(1); even lanes store b32 in
        // TRUE column order
        #pragma unroll
        for (int g = 0; g < 2; ++g)
            #pragma unroll
            for (int r = 0; r < 16; ++r) {
                const int lrow = (r & 3) + 8 * (r >> 2) + 4 * kg;
                const int gi = blk0 + g * 32 + lrow;
                float gbv = gvb_lds[g * 32 + lrow];
                float v0 = acc[g][r] * gbv;              // col f*32 + l31
                float o0 = __shfl_xor(v0, 1);            // col neighbor (l31^1)
                if (gi < E && (l31 & 1) == 0) {
                    *(unsigned*)(m + (size_t)gi * 256 + f * 32 + l31) = pack2(v0, o0);
                }
            }
    }
}

// ---------------- segment sum + feat gather: one wave per dst ----------------
// h[d] = sum_i ( m[i] + ga[i]*feat[src_i] ), TRUE column order: lane owns cols
// [lane*4, lane*4+4) -> one float4 feat load + one ushort4 m load per edge.
__global__ __launch_bounds__(256) void segsum_kernel(
    const int* __restrict__ start, const unsigned short* __restrict__ m,
    const float* __restrict__ ga, const int* __restrict__ esrc_s,
    const float* __restrict__ feat, unsigned short* __restrict__ h, int ND)
{
    int d = blockIdx.x * 4 + (threadIdx.x >> 6);
    if (d >= ND) return;
    int lane = threadIdx.x & 63;
    int coff = lane * 4;               // true-col base for this lane
    int s0 = start[d], s1 = start[d + 1];
    float a0 = 0.f, a1 = 0.f, a2 = 0.f, a3 = 0.f;
    for (int base = s0; base < s1; base += 4) {
        float gav[4], msk[4];
        const float* fp[4];
        const unsigned short* mp[4];
        #pragma unroll
        for (int j = 0; j < 4; ++j) {
            int idx = base + j;
            bool v  = idx < s1;
            int ic  = v ? idx : (s1 - 1);
            msk[j]  = v ? 1.f : 0.f;
            gav[j]  = ga[ic] * msk[j];
            fp[j]   = feat + (size_t)esrc_s[ic] * 256 + coff;
            mp[j]   = m + (size_t)ic * 256 + coff;
        }
        #pragma unroll
        for (int j = 0; j < 4; ++j) {
            float4 fv = *(const float4*)fp[j];
            ushort4 v4 = *(const ushort4*)mp[j];
            a0 += bf2f(v4.x) * msk[j] + fv.x * gav[j];
            a1 += bf2f(v4.y) * msk[j] + fv.y * gav[j];
            a2 += bf2f(v4.z) * msk[j] + fv.z * gav[j];
            a3 += bf2f(v4.w) * msk[j] + fv.w * gav[j];
        }
    }
    ushort4 o; o.x = f2bf(a0); o.y = f2bf(a1); o.z = f2bf(a2); o.w = f2bf(a3);
    *(ushort4*)(h + (size_t)d * 256 + coff) = o;
}

// ---------------- g4: out = (h @ lin_w^T)*ci + b (plain order) ----------------
__global__ __launch_bounds__(256, 2) void g4_kernel(
    const unsigned short* __restrict__ Ab, const unsigned short* __restrict__ lws,
    float* __restrict__ outf, const float* __restrict__ ci,
    const float* __restrict__ bias, int M)
{
    const int lane = threadIdx.x & 63;
    const int wid  = threadIdx.x >> 6;
    const int l31  = lane & 31;
    const int kg   = lane >> 5;
    const int f    = wid & 1;                 // column half
    const int wbase = blockIdx.x * 128 + (wid >> 1) * 64;
    const int r0 = wbase + l31, r1 = wbase + 32 + l31;
    const int ar0 = (r0 < M) ? r0 : (M - 1);
    const int ar1 = (r1 < M) ? r1 : (M - 1);

    f32x16 acc[2][4];
    #pragma unroll
    for (int mi = 0; mi < 2; ++mi)
        #pragma unroll
        for (int n = 0; n < 4; ++n) acc[mi][n] = (f32x16)0.0f;

    #pragma unroll
    for (int ks = 0; ks < 16; ++ks) {
        const int kk = ks * 16 + kg * 8;
        bf16x8 a0 = *(const bf16x8*)(Ab + (size_t)ar0 * 256 + kk);
        bf16x8 a1 = *(const bf16x8*)(Ab + (size_t)ar1 * 256 + kk);
        #pragma unroll
        for (int n = 0; n < 4; ++n) {
            bf16x8 b = ldw(lws, ks, f * 4 + n, kg, l31);
            acc[0][n] = __builtin_amdgcn_mfma_f32_32x32x16_bf16(a0, b, acc[0][n], 0, 0, 0);
            acc[1][n] = __builtin_amdgcn_mfma_f32_32x32x16_bf16(a1, b, acc[1][n], 0, 0, 0);
        }
    }
    #pragma unroll
    for (int mi = 0; mi < 2; ++mi) {
        #pragma unroll
        for (int r = 0; r < 16; ++r) {
            const int gr = wbase + mi * 32 + (r & 3) + 8 * (r >> 2) + 4 * kg;
            if (gr >= M) continue;
            float civ = ci[gr];
            #pragma unroll
            for (int n = 0; n < 4; ++n) {
                int col = f * 128 + n * 32 + l31;
                outf[(size_t)gr * 256 + col] = acc[mi][n][r] * civ + bias[col];
            }
        }
    }
}

extern "C" void kernel_launch(void* const* d_in, const int* in_sizes, int n_in,
                              void* d_out, int out_size, void* d_ws, size_t ws_size,
                              hipStream_t stream) {
    const float* feat = (const float*)d_in[0];
    const float* cj   = (const float*)d_in[1];
    const float* ci   = (const float*)d_in[2];
    const int*   esrc = (const int*)d_in[3];
    const int*   edst = (const int*)d_in[4];
    const int*   rid  = (const int*)d_in[5];
    const float* remb = (const float*)d_in[6];
    const float* pw   = (const float*)d_in[7];
    const float* sw   = (const float*)d_in[8];
    const float* rw1  = (const float*)d_in[9];
    const float* rw2  = (const float*)d_in[10];
    const float* rw3  = (const float*)d_in[11];
    const float* lw   = (const float*)d_in[12];
    const float* lb   = (const float*)d_in[13];
    float* out = (float*)d_out;

    const int E  = in_sizes[3];   // 300000
    const int ND = in_sizes[2];   // 100000

    // workspace carve-up (~210 MB)
    char* ws = (char*)d_ws;
    float* ga = (float*)ws;                               // E f32
    unsigned short* m   = (unsigned short*)(ga + E);      // E*256 bf16 (true cols)
    unsigned short* h   = m + (size_t)E * 256;            // ND*256 bf16 (true cols)
    unsigned short* w1s = h + (size_t)ND * 256;           // 32768
    unsigned short* w2s = w1s + 32768;                    // 65536
    unsigned short* w3s = w2s + 65536;                    // 65536
    unsigned short* lws = w3s + 65536;                    // 65536
    int* cnt    = (int*)(lws + 65536);                    // ND
    int* start  = cnt + ND;                               // ND+1
    int* bsum   = start + ND + 1;                         // 128
    int* within = bsum + 128;                             // E
    int* rid_s  = within + E;                             // E
    int* esrc_s = rid_s + E;                              // E

    const int NB = (ND + 1023) / 1024;

    hipMemsetAsync(cnt, 0, (size_t)ND * sizeof(int), stream);
    prep_weights<<<256, 256, 0, stream>>>(rw1, rw2, rw3, lw, w1s, w2s, w3s, lws);

    // CSR build + direct sorted-edge emit
    hist_kernel<<<(E + 255) / 256, 256, 0, stream>>>(edst, cnt, within, E);
    scan_block<<<NB, 1024, 0, stream>>>(cnt, start, bsum, ND);
    scan_bsum<<<1, 64, 0, stream>>>(bsum, NB);
    add_offsets<<<NB, 1024, 0, stream>>>(start, bsum, ND, E);
    build_sorted<<<(E + 255) / 256, 256, 0, stream>>>(edst, within, start, rid, esrc,
                                                      rid_s, esrc_s, E);

    // fused g1+g2+g3 (8 thin waves, 64 edges/block in 2 groups, weight reuse)
    fused_edge<<<(E + 63) / 64, 512, 0, stream>>>(
        remb, rid_s, esrc_s, w1s, w2s, w3s, pw, sw, cj, ga, m, E);

    // segsum over contiguous sorted rows (1 float4 + 1 ushort4 per edge-lane)
    segsum_kernel<<<(ND + 3) / 4, 256, 0, stream>>>(start, m, ga, esrc_s, feat, h, ND);

    // g4
    g4_kernel<<<(ND + 127) / 128, 256, 0, stream>>>(h, lws, out, ci, lb, ND);
}

// Round 19
// 350.237 us; speedup vs baseline: 1.1157x; 1.1157x over previous
//
#include <hip/hip_runtime.h>
#include <math.h>
#include <stdint.h>

// Fused pipeline (E=300000, ND=100000, FEAT=256, RDIM=128):
//   prep:   weights -> bf16 fragment-ordered tables (plain k order)
//   CSR:    hist, scan, scan_bsum(parallel), add_offsets, build_sorted
//   fused (256 thr = 4 waves by col-half x ... R17 form: f = wave, 2 wf loads,
//          64 edges/block in TWO groups, weight-frag reuse (R16 win), true-col
//          epilogue (R17). launch_bounds(256,3): 140 regs, 3 blk/CU, NO spill.
//          NEW (R19): pa/ra dots computed IN STAGING via 16-lane shfl reduce
//          (each 16-lane group holds one remb row) -> no f==0 imbalance in s1.
//     stage: 64 remb rows coalesced -> cvt_pk -> t_rb bf16; dots -> pdot/rdot LDS
//     ga/gvb: wave 0 (t<64) after staging barrier: sigmoid + cj gather
//     s1 (swapped mfma, K=128): pure MFMA for all waves
//     s2 (swapped, K=256):      t2 = gelu(W2 @ t1)  (t_lds in-place)
//     s3 (normal, K=256):       m = (t2 @ W3^T)*gvb; epilogue pairs (col,col+1)
//         via shfl_xor(1); even lanes store b32 pairs in TRUE column order
//   segsum: h[d] = sum_i ( m[i] + ga[i]*feat[src_i] ) — one float4 feat load +
//           one ushort4 m load per edge-lane; 4-wide masked unroll
//   g4:     out = (h @ lin_w^T)*ci + b
// GELU = x*sigmoid(1.702x); swizzles 16B-slot XOR row&15 (<=2-way, free).
// mfma_f32_32x32x16_bf16 layouts (HW-validated R2-R18):
//   A: row=lane&31, k=8*(lane>>5)+j ; B: col=lane&31, same k
//   D: col=lane&31, row=(reg&3)+8*(reg>>2)+4*(lane>>5)
// Structure notes: 4 fat waves is the local optimum — (256,6)/(512,6) spill
// (R13/R7), 8 thin waves double LDS reads (R18, -33us). Do not revisit.

typedef short bf16x8 __attribute__((ext_vector_type(8)));
typedef float f32x16 __attribute__((ext_vector_type(16)));

__device__ __forceinline__ float bf2f(unsigned short v) {
    union { unsigned int u; float f; } x; x.u = ((unsigned int)v) << 16; return x.f;
}
__device__ __forceinline__ unsigned short f2bf(float f) {
    union { float f; unsigned int u; } x; x.f = f;
    unsigned int u = x.u;
    return (unsigned short)((u + 0x7FFFu + ((u >> 16) & 1u)) >> 16);
}
// single-instruction packed f32x2 -> bf16x2 (RTNE), low16 = lo
__device__ __forceinline__ unsigned pack2(float lo, float hi) {
    unsigned r;
    asm("v_cvt_pk_bf16_f32 %0, %1, %2" : "=v"(r) : "v"(lo), "v"(hi));
    return r;
}
// sigmoid-form GELU: x * sigmoid(1.702 x)
__device__ __forceinline__ float gelu_fast(float x) {
    float e = __builtin_amdgcn_exp2f(x * -2.4554912f);   // exp(-1.702x)
    return x * __builtin_amdgcn_rcpf(e + 1.0f);
}
__device__ __forceinline__ float sigmoidf(float x) {
    return 1.0f / (1.0f + expf(-x));
}

// weights -> bf16 fragment-ordered tables (ALL plain k order)
__global__ __launch_bounds__(256) void prep_weights(
    const float* __restrict__ rw1, const float* __restrict__ rw2,
    const float* __restrict__ rw3, const float* __restrict__ lw,
    unsigned short* __restrict__ w1s, unsigned short* __restrict__ w2s,
    unsigned short* __restrict__ w3s, unsigned short* __restrict__ lws)
{
    int i = blockIdx.x * blockDim.x + threadIdx.x;
    int j   = i & 7;
    int l   = (i >> 3) & 31;
    int kgg = (i >> 8) & 1;
    int n2  = (i >> 9) & 7;
    int ks  = i >> 12;
    if (i < 32768) {   // K=128: ks 0..7
        w1s[i] = f2bf(rw1[(n2 * 32 + l) * 128 + ks * 16 + kgg * 8 + j]);
    }
    if (i < 65536) {   // K=256: ks 0..15
        int row = n2 * 32 + l, k = ks * 16 + kgg * 8 + j;
        w2s[i] = f2bf(rw2[(size_t)row * 256 + k]);
        w3s[i] = f2bf(rw3[(size_t)row * 256 + k]);
        lws[i] = f2bf(lw[(size_t)row * 256 + k]);
    }
}

// fragment load from pre-swizzled table (contiguous, coalesced)
__device__ __forceinline__ bf16x8 ldw(const unsigned short* __restrict__ W,
                                      int ks, int nglob, int kg, int l31) {
    return *(const bf16x8*)(W + (((((ks * 8 + nglob) * 2) + kg) * 32 + l31) << 3));
}

// ---------------- CSR build ----------------
__global__ __launch_bounds__(256) void hist_kernel(
    const int* __restrict__ edst, int* __restrict__ cnt,
    int* __restrict__ within, int E)
{
    int e = blockIdx.x * blockDim.x + threadIdx.x;
    if (e < E) within[e] = atomicAdd(&cnt[edst[e]], 1);
}

__global__ __launch_bounds__(1024) void scan_block(
    const int* __restrict__ cnt, int* __restrict__ start,
    int* __restrict__ bsum, int n)
{
    __shared__ int s[1024];
    int gid = blockIdx.x * 1024 + threadIdx.x;
    int v = (gid < n) ? cnt[gid] : 0;
    s[threadIdx.x] = v;
    __syncthreads();
    #pragma unroll
    for (int off = 1; off < 1024; off <<= 1) {
        int t = (threadIdx.x >= off) ? s[threadIdx.x - off] : 0;
        __syncthreads();
        if (threadIdx.x >= off) s[threadIdx.x] += t;
        __syncthreads();
    }
    if (gid < n) start[gid] = s[threadIdx.x] - v;   // exclusive
    if (threadIdx.x == 1023) bsum[blockIdx.x] = s[1023];
}

// parallel exclusive scan over <=128 block sums (was serial 98-iter loop)
__global__ __launch_bounds__(128) void scan_bsum(int* __restrict__ bsum, int nb) {
    __shared__ int s[128];
    int t = threadIdx.x;
    int v = (t < nb) ? bsum[t] : 0;
    s[t] = v;
    __syncthreads();
    #pragma unroll
    for (int off = 1; off < 128; off <<= 1) {
        int u = (t >= off) ? s[t - off] : 0;
        __syncthreads();
        s[t] += u;
        __syncthreads();
    }
    if (t < nb) bsum[t] = s[t] - v;
}

__global__ __launch_bounds__(1024) void add_offsets(
    int* __restrict__ start, const int* __restrict__ bsum, int n, int E)
{
    int gid = blockIdx.x * 1024 + threadIdx.x;
    if (gid < n) start[gid] += bsum[gid >> 10];
    if (gid == 0) start[n] = E;
}

// counting sort: directly emit dst-sorted rid/esrc
__global__ __launch_bounds__(256) void build_sorted(
    const int* __restrict__ edst, const int* __restrict__ within,
    const int* __restrict__ start, const int* __restrict__ rid,
    const int* __restrict__ esrc, int* __restrict__ rid_s,
    int* __restrict__ esrc_s, int E)
{
    int e = blockIdx.x * blockDim.x + threadIdx.x;
    if (e < E) {
        int pos = start[edst[e]] + within[e];
        rid_s[pos]  = rid[e];
        esrc_s[pos] = esrc[e];
    }
}

// ---------------- LDS helpers (16B-slot XOR swizzle, row&15) ----------------
__device__ __forceinline__ bf16x8 ldtf(const unsigned short* t_lds, int row, int ks, int kg) {
    int slot = (ks * 2 + kg) ^ (row & 15);
    return *(const bf16x8*)((const char*)t_lds + row * 512 + slot * 16);
}
__device__ __forceinline__ void sttf(unsigned short* t_lds, int row, int nn, int p, int kg, uint2 w) {
    int slot = (nn * 4 + p) ^ (row & 15);
    *(uint2*)((char*)t_lds + row * 512 + slot * 16 + kg * 8) = w;
}
__device__ __forceinline__ bf16x8 ldrb(const unsigned short* t_rb, int row, int ks, int kg) {
    int slot = (ks * 2 + kg) ^ (row & 15);
    return *(const bf16x8*)((const char*)t_rb + row * 256 + slot * 16);
}

// ---------------- fused g1+g2+g3 (2 edge-groups, weight-frag reuse) ----------------
__global__ __launch_bounds__(256, 3) void fused_edge(
    const float* __restrict__ remb, const int* __restrict__ rid_s,
    const int* __restrict__ esrc_s,
    const unsigned short* __restrict__ w1s, const unsigned short* __restrict__ w2s,
    const unsigned short* __restrict__ w3s,
    const float* __restrict__ pw, const float* __restrict__ sw,
    const float* __restrict__ cj, float* __restrict__ ga,
    unsigned short* __restrict__ m, int E)
{
    __shared__ __align__(16) unsigned short t_lds[64 * 256];   // 32 KB
    __shared__ __align__(16) unsigned short t_rb[64 * 128];    // 16 KB bf16 remb
    __shared__ float gvb_lds[64];
    __shared__ float pdot_lds[64], rdot_lds[64];

    const int lane = threadIdx.x & 63;
    const int f    = threadIdx.x >> 6;       // wave = col half selector 0..3
    const int l31  = lane & 31;
    const int kg   = lane >> 5;              // 0..1
    const int blk0 = blockIdx.x * 64;

    // ---- stage 64 remb rows coalesced -> t_rb (bf16) + pa/ra dots ----
    {
        const int t = threadIdx.x;
        const int c16 = lane & 15;           // 16B slot = lane&15 (rows align to 16-lane groups)
        const float4 pv0 = *(const float4*)(pw + c16 * 8);
        const float4 pv1 = *(const float4*)(pw + c16 * 8 + 4);
        const float4 sv0 = *(const float4*)(sw + c16 * 8);
        const float4 sv1 = *(const float4*)(sw + c16 * 8 + 4);
        #pragma unroll
        for (int p = 0; p < 4; ++p) {
            int sIdx = p * 256 + t;              // 0..1023
            int row  = sIdx >> 4;                // 0..63 (uniform per 16-lane group)
            int gr   = blk0 + row;
            int rr   = rid_s[(gr < E) ? gr : (E - 1)];
            const float* sp = remb + (size_t)rr * 128 + c16 * 8;
            float4 a = *(const float4*)sp;
            float4 b = *(const float4*)(sp + 4);
            // dot partials for this row's 8-element slice
            float pd = a.x*pv0.x + a.y*pv0.y + a.z*pv0.z + a.w*pv0.w
                     + b.x*pv1.x + b.y*pv1.y + b.z*pv1.z + b.w*pv1.w;
            float rd = a.x*sv0.x + a.y*sv0.y + a.z*sv0.z + a.w*sv0.w
                     + b.x*sv1.x + b.y*sv1.y + b.z*sv1.z + b.w*sv1.w;
            #pragma unroll
            for (int off = 8; off >= 1; off >>= 1) {
                pd += __shfl_xor(pd, off);
                rd += __shfl_xor(rd, off);
            }
            if (c16 == 0) { pdot_lds[row] = pd; rdot_lds[row] = rd; }
            uint4 w;
            w.x = pack2(a.x, a.y); w.y = pack2(a.z, a.w);
            w.z = pack2(b.x, b.y); w.w = pack2(b.z, b.w);
            int slot = c16 ^ (row & 15);
            *(uint4*)((char*)t_rb + row * 256 + slot * 16) = w;
        }
    }
    __syncthreads();

    // ---- ga/gvb from staged dots (wave 0, t<64; consumed in s3 after barriers) ----
    if (threadIdx.x < 64) {
        int i = blk0 + (int)threadIdx.x;
        int ic = (i < E) ? i : (E - 1);
        float cjv = cj[esrc_s[ic]];
        float gav = sigmoidf(pdot_lds[threadIdx.x]) * cjv;
        gvb_lds[threadIdx.x] = sigmoidf(rdot_lds[threadIdx.x]) * cjv;
        if (i < E) ga[i] = gav;
    }

    // ================= stage 1: swapped, K=128 (pure MFMA, balanced) =================
    {
        f32x16 acc[2][2];
        #pragma unroll
        for (int g = 0; g < 2; ++g) { acc[g][0] = (f32x16)0.0f; acc[g][1] = (f32x16)0.0f; }

        #pragma unroll
        for (int ks = 0; ks < 8; ++ks) {
            bf16x8 wf0 = ldw(w1s, ks, f * 2 + 0, kg, l31);
            bf16x8 wf1 = ldw(w1s, ks, f * 2 + 1, kg, l31);
            #pragma unroll
            for (int g = 0; g < 2; ++g) {
                bf16x8 af = ldrb(t_rb, g * 32 + l31, ks, kg);
                acc[g][0] = __builtin_amdgcn_mfma_f32_32x32x16_bf16(wf0, af, acc[g][0], 0, 0, 0);
                acc[g][1] = __builtin_amdgcn_mfma_f32_32x32x16_bf16(wf1, af, acc[g][1], 0, 0, 0);
            }
        }

        #pragma unroll
        for (int g = 0; g < 2; ++g)
            #pragma unroll
            for (int n = 0; n < 2; ++n)
                #pragma unroll
                for (int p = 0; p < 4; ++p) {
                    uint2 w;
                    w.x = pack2(gelu_fast(acc[g][n][4*p + 0]), gelu_fast(acc[g][n][4*p + 1]));
                    w.y = pack2(gelu_fast(acc[g][n][4*p + 2]), gelu_fast(acc[g][n][4*p + 3]));
                    sttf(t_lds, g * 32 + l31, f * 2 + n, p, kg, w);
                }
    }
    __syncthreads();

    // ================= stage 2: swapped, K=256, LDS in-place =================
    {
        f32x16 acc[2][2];
        #pragma unroll
        for (int g = 0; g < 2; ++g) { acc[g][0] = (f32x16)0.0f; acc[g][1] = (f32x16)0.0f; }

        #pragma unroll
        for (int ks = 0; ks < 16; ++ks) {
            bf16x8 wf0 = ldw(w2s, ks, f * 2 + 0, kg, l31);
            bf16x8 wf1 = ldw(w2s, ks, f * 2 + 1, kg, l31);
            #pragma unroll
            for (int g = 0; g < 2; ++g) {
                bf16x8 tf = ldtf(t_lds, g * 32 + l31, ks, kg);
                acc[g][0] = __builtin_amdgcn_mfma_f32_32x32x16_bf16(wf0, tf, acc[g][0], 0, 0, 0);
                acc[g][1] = __builtin_amdgcn_mfma_f32_32x32x16_bf16(wf1, tf, acc[g][1], 0, 0, 0);
            }
        }
        __syncthreads();   // all reads of t1 done before overwrite
        #pragma unroll
        for (int g = 0; g < 2; ++g)
            #pragma unroll
            for (int n = 0; n < 2; ++n)
                #pragma unroll
                for (int p = 0; p < 4; ++p) {
                    uint2 w;
                    w.x = pack2(gelu_fast(acc[g][n][4*p + 0]), gelu_fast(acc[g][n][4*p + 1]));
                    w.y = pack2(gelu_fast(acc[g][n][4*p + 2]), gelu_fast(acc[g][n][4*p + 3]));
                    sttf(t_lds, g * 32 + l31, f * 2 + n, p, kg, w);
                }
    }
    __syncthreads();

    // ============ stage 3: normal, K=256, m = rf*gvb (true col order) ============
    {
        f32x16 acc[2][2];
        #pragma unroll
        for (int g = 0; g < 2; ++g) { acc[g][0] = (f32x16)0.0f; acc[g][1] = (f32x16)0.0f; }

        #pragma unroll
        for (int ks = 0; ks < 16; ++ks) {
            bf16x8 wf0 = ldw(w3s, ks, f * 2 + 0, kg, l31);
            bf16x8 wf1 = ldw(w3s, ks, f * 2 + 1, kg, l31);
            #pragma unroll
            for (int g = 0; g < 2; ++g) {
                bf16x8 tf = ldtf(t_lds, g * 32 + l31, ks, kg);
                acc[g][0] = __builtin_amdgcn_mfma_f32_32x32x16_bf16(tf, wf0, acc[g][0], 0, 0, 0);
                acc[g][1] = __builtin_amdgcn_mfma_f32_32x32x16_bf16(tf, wf1, acc[g][1], 0, 0, 0);
            }
        }

        // epilogue: pair (col, col+1) via shfl_xor(1); even lanes store b32 in
        // TRUE column order (even-lane dwords form contiguous 64B runs per row)
        #pragma unroll
        for (int g = 0; g < 2; ++g)
            #pragma unroll
            for (int r = 0; r < 16; ++r) {
                const int lrow = (r & 3) + 8 * (r >> 2) + 4 * kg;
                const int gi = blk0 + g * 32 + lrow;
                float gbv = gvb_lds[g * 32 + lrow];
                float v0 = acc[g][0][r] * gbv;           // col f*64 + l31
                float v1 = acc[g][1][r] * gbv;           // col f*64 + 32 + l31
                float o0 = __shfl_xor(v0, 1);            // col neighbor (l31^1)
                float o1 = __shfl_xor(v1, 1);
                if (gi < E && (l31 & 1) == 0) {
                    unsigned short* mp = m + (size_t)gi * 256 + f * 64 + l31;
                    *(unsigned*)mp        = pack2(v0, o0);
                    *(unsigned*)(mp + 32) = pack2(v1, o1);
                }
            }
    }
}

// ---------------- segment sum + feat gather: one wave per dst ----------------
// h[d] = sum_i ( m[i] + ga[i]*feat[src_i] ), TRUE column order: lane owns cols
// [lane*4, lane*4+4) -> one float4 feat load + one ushort4 m load per edge.
__global__ __launch_bounds__(256) void segsum_kernel(
    const int* __restrict__ start, const unsigned short* __restrict__ m,
    const float* __restrict__ ga, const int* __restrict__ esrc_s,
    const float* __restrict__ feat, unsigned short* __restrict__ h, int ND)
{
    int d = blockIdx.x * 4 + (threadIdx.x >> 6);
    if (d >= ND) return;
    int lane = threadIdx.x & 63;
    int coff = lane * 4;               // true-col base for this lane
    int s0 = start[d], s1 = start[d + 1];
    float a0 = 0.f, a1 = 0.f, a2 = 0.f, a3 = 0.f;
    for (int base = s0; base < s1; base += 4) {
        float gav[4], msk[4];
        const float* fp[4];
        const unsigned short* mp[4];
        #pragma unroll
        for (int j = 0; j < 4; ++j) {
            int idx = base + j;
            bool v  = idx < s1;
            int ic  = v ? idx : (s1 - 1);
            msk[j]  = v ? 1.f : 0.f;
            gav[j]  = ga[ic] * msk[j];
            fp[j]   = feat + (size_t)esrc_s[ic] * 256 + coff;
            mp[j]   = m + (size_t)ic * 256 + coff;
        }
        #pragma unroll
        for (int j = 0; j < 4; ++j) {
            float4 fv = *(const float4*)fp[j];
            ushort4 v4 = *(const ushort4*)mp[j];
            a0 += bf2f(v4.x) * msk[j] + fv.x * gav[j];
            a1 += bf2f(v4.y) * msk[j] + fv.y * gav[j];
            a2 += bf2f(v4.z) * msk[j] + fv.z * gav[j];
            a3 += bf2f(v4.w) * msk[j] + fv.w * gav[j];
        }
    }
    ushort4 o; o.x = f2bf(a0); o.y = f2bf(a1); o.z = f2bf(a2); o.w = f2bf(a3);
    *(ushort4*)(h + (size_t)d * 256 + coff) = o;
}

// ---------------- g4: out = (h @ lin_w^T)*ci + b (plain order) ----------------
__global__ __launch_bounds__(256, 2) void g4_kernel(
    const unsigned short* __restrict__ Ab, const unsigned short* __restrict__ lws,
    float* __restrict__ outf, const float* __restrict__ ci,
    const float* __restrict__ bias, int M)
{
    const int lane = threadIdx.x & 63;
    const int wid  = threadIdx.x >> 6;
    const int l31  = lane & 31;
    const int kg   = lane >> 5;
    const int f    = wid & 1;                 // column half
    const int wbase = blockIdx.x * 128 + (wid >> 1) * 64;
    const int r0 = wbase + l31, r1 = wbase + 32 + l31;
    const int ar0 = (r0 < M) ? r0 : (M - 1);
    const int ar1 = (r1 < M) ? r1 : (M - 1);

    f32x16 acc[2][4];
    #pragma unroll
    for (int mi = 0; mi < 2; ++mi)
        #pragma unroll
        for (int n = 0; n < 4; ++n) acc[mi][n] = (f32x16)0.0f;

    #pragma unroll
    for (int ks = 0; ks < 16; ++ks) {
        const int kk = ks * 16 + kg * 8;
        bf16x8 a0 = *(const bf16x8*)(Ab + (size_t)ar0 * 256 + kk);
        bf16x8 a1 = *(const bf16x8*)(Ab + (size_t)ar1 * 256 + kk);
        #pragma unroll
        for (int n = 0; n < 4; ++n) {
            bf16x8 b = ldw(lws, ks, f * 4 + n, kg, l31);
            acc[0][n] = __builtin_amdgcn_mfma_f32_32x32x16_bf16(a0, b, acc[0][n], 0, 0, 0);
            acc[1][n] = __builtin_amdgcn_mfma_f32_32x32x16_bf16(a1, b, acc[1][n], 0, 0, 0);
        }
    }
    #pragma unroll
    for (int mi = 0; mi < 2; ++mi) {
        #pragma unroll
        for (int r = 0; r < 16; ++r) {
            const int gr = wbase + mi * 32 + (r & 3) + 8 * (r >> 2) + 4 * kg;
            if (gr >= M) continue;
            float civ = ci[gr];
            #pragma unroll
            for (int n = 0; n < 4; ++n) {
                int col = f * 128 + n * 32 + l31;
                outf[(size_t)gr * 256 + col] = acc[mi][n][r] * civ + bias[col];
            }
        }
    }
}

extern "C" void kernel_launch(void* const* d_in, const int* in_sizes, int n_in,
                              void* d_out, int out_size, void* d_ws, size_t ws_size,
                              hipStream_t stream) {
    const float* feat = (const float*)d_in[0];
    const float* cj   = (const float*)d_in[1];
    const float* ci   = (const float*)d_in[2];
    const int*   esrc = (const int*)d_in[3];
    const int*   edst = (const int*)d_in[4];
    const int*   rid  = (const int*)d_in[5];
    const float* remb = (const float*)d_in[6];
    const float* pw   = (const float*)d_in[7];
    const float* sw   = (const float*)d_in[8];
    const float* rw1  = (const float*)d_in[9];
    const float* rw2  = (const float*)d_in[10];
    const float* rw3  = (const float*)d_in[11];
    const float* lw   = (const float*)d_in[12];
    const float* lb   = (const float*)d_in[13];
    float* out = (float*)d_out;

    const int E  = in_sizes[3];   // 300000
    const int ND = in_sizes[2];   // 100000

    // workspace carve-up (~210 MB)
    char* ws = (char*)d_ws;
    float* ga = (float*)ws;                               // E f32
    unsigned short* m   = (unsigned short*)(ga + E);      // E*256 bf16 (true cols)
    unsigned short* h   = m + (size_t)E * 256;            // ND*256 bf16 (true cols)
    unsigned short* w1s = h + (size_t)ND * 256;           // 32768
    unsigned short* w2s = w1s + 32768;                    // 65536
    unsigned short* w3s = w2s + 65536;                    // 65536
    unsigned short* lws = w3s + 65536;                    // 65536
    int* cnt    = (int*)(lws + 65536);                    // ND
    int* start  = cnt + ND;                               // ND+1
    int* bsum   = start + ND + 1;                         // 128
    int* within = bsum + 128;                             // E
    int* rid_s  = within + E;                             // E
    int* esrc_s = rid_s + E;                              // E

    const int NB = (ND + 1023) / 1024;

    hipMemsetAsync(cnt, 0, (size_t)ND * sizeof(int), stream);
    prep_weights<<<256, 256, 0, stream>>>(rw1, rw2, rw3, lw, w1s, w2s, w3s, lws);

    // CSR build + direct sorted-edge emit
    hist_kernel<<<(E + 255) / 256, 256, 0, stream>>>(edst, cnt, within, E);
    scan_block<<<NB, 1024, 0, stream>>>(cnt, start, bsum, ND);
    scan_bsum<<<1, 128, 0, stream>>>(bsum, NB);
    add_offsets<<<NB, 1024, 0, stream>>>(start, bsum, ND, E);
    build_sorted<<<(E + 255) / 256, 256, 0, stream>>>(edst, within, start, rid, esrc,
                                                      rid_s, esrc_s, E);

    // fused g1+g2+g3 (4 waves, 64 edges/block, weight reuse, dots-in-staging)
    fused_edge<<<(E + 63) / 64, 256, 0, stream>>>(
        remb, rid_s, esrc_s, w1s, w2s, w3s, pw, sw, cj, ga, m, E);

    // segsum over contiguous sorted rows (1 float4 + 1 ushort4 per edge-lane)
    segsum_kernel<<<(ND + 3) / 4, 256, 0, stream>>>(start, m, ga, esrc_s, feat, h, ND);

    // g4
    g4_kernel<<<(ND + 127) / 128, 256, 0, stream>>>(h, lws, out, ci, lb, ND);
}